// Round 10
// baseline (94.735 us; speedup 1.0000x reference)
//
#include <hip/hip_runtime.h>

// CARAFE upsample, N=2 C=256 H=W=128, K=5 S=2 G=1, f32 in/out.
// R9: OCCUPANCY over register hoarding. R0-R8 all sat at 2 waves/SIMD
// (~24% occupancy) because 100 masks/thread + staging ate ~180 regs; every
// pipelining trick failed because nothing hides latency at 2 waves/SIMD.
// Now: 1 output pixel/thread, 25 masks/thread. Block = 256 thr = 16x16
// output tile; source tile 12x12 floats/channel staged double-buffered in
// LDS (1 coalesced load/thread). Per channel: 25 conflict-free LDS reads
// (16 distinct addrs/wave, 4-way broadcast groups) + 25 FMA + 1 NT store.
// __launch_bounds__(256,4) -> <=128 regs -> 4 waves/SIMD = 2x occupancy.

namespace {
constexpr int N_ = 2, C_ = 256, H_ = 128, W_ = 128;
constexpr int K_ = 5, S_ = 2, PAD_ = 2;
constexpr int SH_ = H_ * S_, SW_ = W_ * S_;      // 256, 256
constexpr int CPB = 16;                          // channels per block
constexpr int TPB = 256;
constexpr int TOH = 16, TOW = 16;                // output tile per block
constexpr int SRW = TOW / 2 + 2 * PAD_;          // 12 src cols
constexpr int SRH = TOH / 2 + 2 * PAD_;          // 12 src rows
constexpr int TSZ = SRH * SRW;                   // 144 floats per channel
constexpr int SPB = N_ * (SH_ / TOH) * (SW_ / TOW);  // 512 spatial blocks
}

__global__ __launch_bounds__(TPB, 4) void carafe_kernel(
    const float* __restrict__ feat,
    const float* __restrict__ masks,
    float* __restrict__ out)
{
    __shared__ float lds[2][TSZ];

    const int t    = threadIdx.x;
    const int sp   = blockIdx.x;
    const int n    = sp >> 8;                 // 256 tiles per image
    const int tile = sp & 255;
    const int ty   = tile >> 4, tx = tile & 15;
    const int oh0  = ty * TOH, ow0 = tx * TOW;
    const int ory  = t >> 4, ocx = t & 15;    // thread's output coords in tile
    const int oh   = oh0 + ory, ow = ow0 + ocx;
    const int c0   = blockIdx.y * CPB;

    // ---- staging descriptor: thread t stages tile element t (t < 144)
    const int sy0 = (oh0 >> 1) - PAD_, sx0 = (ow0 >> 1) - PAD_;
    const bool in = (t < TSZ);
    const int r  = t / SRW, cc = t % SRW;     // only meaningful if in
    const int gy = sy0 + r, gx = sx0 + cc;
    const bool ok = in && ((unsigned)gy < (unsigned)H_) && ((unsigned)gx < (unsigned)W_);
    const int goff = ok ? (gy * W_ + gx) : 0;

    // ---- this thread's 25 mask weights (register-resident, small)
    float mk[25];
    {
        const float* mb = masks + (size_t)n * 25 * (SH_ * SW_) + oh * SW_ + ow;
#pragma unroll
        for (int k = 0; k < 25; ++k) mk[k] = mb[(size_t)k * (SH_ * SW_)];
    }

    // LDS read base: top-left tap of this thread's 5x5 window
    const int rb = (ory >> 1) * SRW + (ocx >> 1);

    const float* fb = feat + ((size_t)n * C_ + c0) * (H_ * W_);
    float*       ob = out + (((size_t)n * C_ + c0) * SH_ + oh) * SW_ + ow;

    // ---- prologue: channel 0 into buffer 0
    if (in) lds[0][t] = ok ? fb[goff] : 0.f;
    __syncthreads();

    for (int c = 0; c < CPB; ++c) {
        const int cur = c & 1;

        // prefetch next channel's tile element to register
        float nxt = 0.f;
        if (c + 1 < CPB && in) nxt = ok ? fb[(size_t)(c + 1) * (H_ * W_) + goff] : 0.f;

        // compute from LDS: 25 taps
        const float* L = &lds[cur][rb];
        float acc = 0.f;
#pragma unroll
        for (int di = 0; di < K_; ++di) {
#pragma unroll
            for (int dj = 0; dj < K_; ++dj) {
                acc = fmaf(L[di * SRW + dj], mk[di * K_ + dj], acc);
            }
        }
        __builtin_nontemporal_store(acc, ob + (size_t)c * (SH_ * SW_));

        // land next channel into the other buffer
        if (c + 1 < CPB && in) lds[cur ^ 1][t] = nxt;
        __syncthreads();
    }
}

extern "C" void kernel_launch(void* const* d_in, const int* in_sizes, int n_in,
                              void* d_out, int out_size, void* d_ws, size_t ws_size,
                              hipStream_t stream) {
    const float* feat  = (const float*)d_in[0];
    const float* masks = (const float*)d_in[1];
    float* out = (float*)d_out;
    dim3 grid(SPB, C_ / CPB);                 // (512, 16) = 8192 blocks
    carafe_kernel<<<grid, dim3(TPB), 0, stream>>>(feat, masks, out);
}

// Round 11
// 73.973 us; speedup vs baseline: 1.2807x; 1.2807x over previous
//
#include <hip/hip_runtime.h>

// CARAFE upsample, N=2 C=256 H=W=128, K=5 S=2 G=1, f32 in/out.
// R10: quad design + bf16-PACKED masks. Evidence so far:
//   - quad (2x2 outputs/thread) is mandatory: R9 (1 output/thread) proved
//     25 LDS reads/output saturates the LDS pipe (124us est vs 116us meas).
//   - 100 f32 mask regs are fatal: R0-R8 sat at 2 waves/SIMD, latency-bound.
// Fix: pack the 4x25 masks as 50 VGPRs of 2xbf16 (RNE pack; unpack = 1 VALU
// op/value, rematerializable -> no pressure). __launch_bounds__(256,4) caps
// regs at 128 -> 4 waves/SIMD = 2x all prior rounds. Structure = R5 (proven
// correct): 4-wave block, 2 src rows x 128 cols, depth-2 prefetch, barrier
// per channel. Mask bf16 error <= max|f|*2^-9 ~ 0.009 << 0.026 threshold.

namespace {
constexpr int N_ = 2, C_ = 256, H_ = 128, W_ = 128;
constexpr int K_ = 5, S_ = 2, PAD_ = 2;
constexpr int SH_ = H_ * S_, SW_ = W_ * S_;          // 256, 256
constexpr int CPB = 32;                              // channels per block
constexpr int TPB = 256;
constexpr int RPB = 2;                               // source rows per block
constexpr int HB_ = H_ / RPB;                        // 64 row-blocks
constexpr int LW  = W_ + 2 * PAD_;                   // 132
constexpr int LROWS = RPB + 2 * PAD_;                // 6
constexpr int LSZ = LROWS * LW;                      // 792
constexpr int NSLOT = (LSZ + TPB - 1) / TPB;         // 4
typedef float v2f __attribute__((ext_vector_type(2)));

__device__ __forceinline__ unsigned pack_bf16(float hi, float lo) {
    unsigned uh = __float_as_uint(hi), ul = __float_as_uint(lo);
    return ((uh + 0x8000u) & 0xFFFF0000u) | ((ul + 0x8000u) >> 16);
}
__device__ __forceinline__ float up_hi(unsigned p) {
    return __uint_as_float(p & 0xFFFF0000u);
}
__device__ __forceinline__ float up_lo(unsigned p) {
    return __uint_as_float(p << 16);
}
}

__global__ __launch_bounds__(TPB, 4) void carafe_kernel(
    const float* __restrict__ feat,
    const float* __restrict__ masks,
    float* __restrict__ out)
{
    __shared__ float lds[2][LSZ];

    const int bx = blockIdx.x;
    const int n  = bx / HB_;                  // block-uniform
    const int h0 = (bx % HB_) * RPB;
    const int t  = threadIdx.x;
    const int hl = t >> 7;                    // 0..1
    const int w  = t & (W_ - 1);
    const int h  = h0 + hl;
    const int c0 = blockIdx.y * CPB;

    // ---- staging descriptors (invariant over channels)
    int  goff[NSLOT];
    bool gval[NSLOT];
#pragma unroll
    for (int s = 0; s < NSLOT; ++s) {
        int idx = s * TPB + t;
        int r  = idx / LW, cc = idx % LW;
        int gy = h0 - PAD_ + r, gx = cc - PAD_;
        bool ok = (idx < LSZ) && ((unsigned)gy < (unsigned)H_) && ((unsigned)gx < (unsigned)W_);
        gval[s] = ok;
        goff[s] = ok ? (gy * W_ + gx) : 0;
    }

    // ---- 100 mask weights packed into 50 VGPRs (2 x bf16 each)
    unsigned pk01[25], pk23[25];     // (top-left, top-right), (bot-left, bot-right)
    {
        const float* mb = masks + ((size_t)n * 25) * (SH_ * SW_)
                                + (size_t)(S_ * h) * SW_ + S_ * w;
#pragma unroll
        for (int k = 0; k < 25; ++k) {
            v2f tt = *(const v2f*)(mb + (size_t)k * (SH_ * SW_));
            v2f bb = *(const v2f*)(mb + (size_t)k * (SH_ * SW_) + SW_);
            pk01[k] = pack_bf16(tt.x, tt.y);
            pk23[k] = pack_bf16(bb.x, bb.y);
        }
    }

    const float* fb = feat + ((size_t)n * C_ + c0) * (H_ * W_);
    float*       ob = out + (((size_t)n * C_ + c0) * SH_ + (size_t)(S_ * h)) * SW_ + S_ * w;

    auto issue = [&](int c, float* st) {
        const float* f = fb + (size_t)c * (H_ * W_);
#pragma unroll
        for (int s = 0; s < NSLOT; ++s) st[s] = gval[s] ? f[goff[s]] : 0.f;
    };
    auto land = [&](int b, const float* st) {
#pragma unroll
        for (int s = 0; s < NSLOT; ++s) {
            int idx = s * TPB + t;
            if (idx < LSZ) lds[b][idx] = st[s];
        }
    };
    auto compute_store = [&](const float* __restrict__ L, int c) {
        float a0 = 0.f, a1 = 0.f, a2 = 0.f, a3 = 0.f;
#pragma unroll
        for (int di = 0; di < K_; ++di) {
            const float* Lr = L + (hl + di) * LW + w;
            float f0 = Lr[0], f1 = Lr[1], f2 = Lr[2], f3 = Lr[3], f4 = Lr[4];
            const int kb = di * K_;
#pragma unroll
            for (int dj = 0; dj < K_; ++dj) {
                float f = (dj == 0) ? f0 : (dj == 1) ? f1 : (dj == 2) ? f2
                        : (dj == 3) ? f3 : f4;
                unsigned p01 = pk01[kb + dj], p23 = pk23[kb + dj];
                a0 = fmaf(f, up_hi(p01), a0);
                a1 = fmaf(f, up_lo(p01), a1);
                a2 = fmaf(f, up_hi(p23), a2);
                a3 = fmaf(f, up_lo(p23), a3);
            }
        }
        float* oc = ob + (size_t)c * ((size_t)SH_ * SW_);
        v2f top = {a0, a1}, bot = {a2, a3};
        __builtin_nontemporal_store(top, (v2f*)oc);
        __builtin_nontemporal_store(bot, (v2f*)(oc + SW_));
    };

    // ---- prologue: channel 0 straight into LDS[0]; channel 1 into stA
    float stA[NSLOT], stB[NSLOT];
#pragma unroll
    for (int s = 0; s < NSLOT; ++s) {
        int idx = s * TPB + t;
        if (idx < LSZ) lds[0][idx] = gval[s] ? fb[goff[s]] : 0.f;
    }
    issue(1, stA);

    for (int c2 = 0; c2 < CPB; c2 += 2) {
        // even channel: compute lds[0] = c2; stA holds c2+1 (in flight)
        __syncthreads();                       // lds[0] writes visible
        if (c2 + 2 < CPB) issue(c2 + 2, stB);  // 2-deep prefetch
        compute_store(&lds[0][0], c2);
        land(1, stA);                          // c2+1 -> lds[1]

        // odd channel: compute lds[1] = c2+1; stB holds c2+2 (in flight)
        __syncthreads();
        if (c2 + 3 < CPB) issue(c2 + 3, stA);
        compute_store(&lds[1][0], c2 + 1);
        if (c2 + 2 < CPB) land(0, stB);        // c2+2 -> lds[0]
    }
}

extern "C" void kernel_launch(void* const* d_in, const int* in_sizes, int n_in,
                              void* d_out, int out_size, void* d_ws, size_t ws_size,
                              hipStream_t stream) {
    const float* feat  = (const float*)d_in[0];
    const float* masks = (const float*)d_in[1];
    float* out = (float*)d_out;
    dim3 grid(N_ * HB_, C_ / CPB);            // (128, 8) = 1024 blocks
    carafe_kernel<<<grid, dim3(TPB), 0, stream>>>(feat, masks, out);
}

// Round 12
// 56.915 us; speedup vs baseline: 1.6645x; 1.2997x over previous
//
#include <hip/hip_runtime.h>

// CARAFE upsample, N=2 C=256 H=W=128, K=5 S=2 G=1, f32 in/out.
// R11: R5 (proven-correct 57us base) with ONE change: __syncthreads() ->
// {s_waitcnt lgkmcnt(0); s_barrier} (raw builtin). __syncthreads emits
// s_waitcnt vmcnt(0) lgkmcnt(0) before s_barrier, draining the depth-2
// prefetch at every channel iteration (~700cyc HBM latency exposed, only 2
// blocks/CU to cover it) -- that drain is why R5's prefetch bought nothing.
// lgkmcnt(0)+s_barrier preserves all LDS ordering (each wave's ds_reads AND
// ds_writes retire before the barrier); prefetch loads + NT stores stay in
// flight, consumed later via compiler-counted vmcnt. R8 proved this fencing
// is functionally correct; R5 supplies the efficient block geometry.

namespace {
constexpr int N_ = 2, C_ = 256, H_ = 128, W_ = 128;
constexpr int K_ = 5, S_ = 2, PAD_ = 2;
constexpr int SH_ = H_ * S_, SW_ = W_ * S_;          // 256, 256
constexpr int CPB = 16;                              // channels per block
constexpr int TPB = 256;
constexpr int RPB = 2;                               // source rows per block
constexpr int HB_ = H_ / RPB;                        // 64 row-blocks
constexpr int LW  = W_ + 2 * PAD_;                   // 132
constexpr int LROWS = RPB + 2 * PAD_;                // 6
constexpr int LSZ = LROWS * LW;                      // 792
constexpr int NSLOT = (LSZ + TPB - 1) / TPB;         // 4
typedef float v2f __attribute__((ext_vector_type(2)));
}

// __syncthreads() minus the vmcnt(0) drain: LDS ops retired, then barrier.
// sched_barrier(0) fences the MIR scheduler (rule #18: compiler can hoist
// LDS ops past inline-asm waitcnts).
__device__ __forceinline__ void block_sync_lds() {
    __builtin_amdgcn_sched_barrier(0);
    asm volatile("s_waitcnt lgkmcnt(0)" ::: "memory");
    __builtin_amdgcn_s_barrier();
    __builtin_amdgcn_sched_barrier(0);
}

__global__ __launch_bounds__(TPB, 2) void carafe_kernel(
    const float* __restrict__ feat,
    const float* __restrict__ masks,
    float* __restrict__ out)
{
    __shared__ float lds[2][LSZ];

    const int bx = blockIdx.x;
    const int n  = bx / HB_;                  // block-uniform
    const int h0 = (bx % HB_) * RPB;
    const int t  = threadIdx.x;
    const int hl = t >> 7;                    // 0..1
    const int w  = t & (W_ - 1);
    const int h  = h0 + hl;
    const int c0 = blockIdx.y * CPB;

    // ---- staging descriptors (invariant over channels)
    int  goff[NSLOT];
    bool gval[NSLOT];
#pragma unroll
    for (int s = 0; s < NSLOT; ++s) {
        int idx = s * TPB + t;
        int r  = idx / LW, cc = idx % LW;
        int gy = h0 - PAD_ + r, gx = cc - PAD_;
        bool ok = (idx < LSZ) && ((unsigned)gy < (unsigned)H_) && ((unsigned)gx < (unsigned)W_);
        gval[s] = ok;
        goff[s] = ok ? (gy * W_ + gx) : 0;
    }

    // ---- 100 mask weights for this thread's 2x2 output quad
    float m0[25], m1[25], m2[25], m3[25];
    {
        const float* mb = masks + ((size_t)n * 25) * (SH_ * SW_)
                                + (size_t)(S_ * h) * SW_ + S_ * w;
#pragma unroll
        for (int k = 0; k < 25; ++k) {
            v2f tt = *(const v2f*)(mb + (size_t)k * (SH_ * SW_));
            v2f bb = *(const v2f*)(mb + (size_t)k * (SH_ * SW_) + SW_);
            m0[k] = tt.x; m1[k] = tt.y; m2[k] = bb.x; m3[k] = bb.y;
        }
    }

    const float* fb = feat + ((size_t)n * C_ + c0) * (H_ * W_);
    float*       ob = out + (((size_t)n * C_ + c0) * SH_ + (size_t)(S_ * h)) * SW_ + S_ * w;

    auto issue = [&](int c, float* st) {
        const float* f = fb + (size_t)c * (H_ * W_);
#pragma unroll
        for (int s = 0; s < NSLOT; ++s) st[s] = gval[s] ? f[goff[s]] : 0.f;
    };
    auto land = [&](int b, const float* st) {
#pragma unroll
        for (int s = 0; s < NSLOT; ++s) {
            int idx = s * TPB + t;
            if (idx < LSZ) lds[b][idx] = st[s];
        }
    };
    auto compute_store = [&](const float* __restrict__ L, int c) {
        float a0 = 0.f, a1 = 0.f, a2 = 0.f, a3 = 0.f;
#pragma unroll
        for (int di = 0; di < K_; ++di) {
            const float* Lr = L + (hl + di) * LW + w;
            float f0 = Lr[0], f1 = Lr[1], f2 = Lr[2], f3 = Lr[3], f4 = Lr[4];
            const int kb = di * K_;
            a0 = fmaf(f0, m0[kb + 0], a0);
            a1 = fmaf(f0, m1[kb + 0], a1);
            a2 = fmaf(f0, m2[kb + 0], a2);
            a3 = fmaf(f0, m3[kb + 0], a3);
            a0 = fmaf(f1, m0[kb + 1], a0);
            a1 = fmaf(f1, m1[kb + 1], a1);
            a2 = fmaf(f1, m2[kb + 1], a2);
            a3 = fmaf(f1, m3[kb + 1], a3);
            a0 = fmaf(f2, m0[kb + 2], a0);
            a1 = fmaf(f2, m1[kb + 2], a1);
            a2 = fmaf(f2, m2[kb + 2], a2);
            a3 = fmaf(f2, m3[kb + 2], a3);
            a0 = fmaf(f3, m0[kb + 3], a0);
            a1 = fmaf(f3, m1[kb + 3], a1);
            a2 = fmaf(f3, m2[kb + 3], a2);
            a3 = fmaf(f3, m3[kb + 3], a3);
            a0 = fmaf(f4, m0[kb + 4], a0);
            a1 = fmaf(f4, m1[kb + 4], a1);
            a2 = fmaf(f4, m2[kb + 4], a2);
            a3 = fmaf(f4, m3[kb + 4], a3);
        }
        float* oc = ob + (size_t)c * ((size_t)SH_ * SW_);
        v2f top = {a0, a1}, bot = {a2, a3};
        __builtin_nontemporal_store(top, (v2f*)oc);
        __builtin_nontemporal_store(bot, (v2f*)(oc + SW_));
    };

    // ---- prologue: channel 0 straight into LDS[0]; channel 1 into stA
    float stA[NSLOT], stB[NSLOT];
#pragma unroll
    for (int s = 0; s < NSLOT; ++s) {
        int idx = s * TPB + t;
        if (idx < LSZ) lds[0][idx] = gval[s] ? fb[goff[s]] : 0.f;
    }
    issue(1, stA);

    for (int c2 = 0; c2 < CPB; c2 += 2) {
        // even channel: compute lds[0] = c2; stA holds c2+1 (in flight)
        block_sync_lds();                      // lds[0] writes visible, no vm drain
        if (c2 + 2 < CPB) issue(c2 + 2, stB);  // 2-deep prefetch
        compute_store(&lds[0][0], c2);
        land(1, stA);                          // c2+1 -> lds[1], counted vmcnt wait

        // odd channel: compute lds[1] = c2+1; stB holds c2+2 (in flight)
        block_sync_lds();
        if (c2 + 3 < CPB) issue(c2 + 3, stA);
        compute_store(&lds[1][0], c2 + 1);
        if (c2 + 2 < CPB) land(0, stB);        // c2+2 -> lds[0]
    }
}

extern "C" void kernel_launch(void* const* d_in, const int* in_sizes, int n_in,
                              void* d_out, int out_size, void* d_ws, size_t ws_size,
                              hipStream_t stream) {
    const float* feat  = (const float*)d_in[0];
    const float* masks = (const float*)d_in[1];
    float* out = (float*)d_out;
    dim3 grid(N_ * HB_, C_ / CPB);            // (128, 16) = 2048 blocks
    carafe_kernel<<<grid, dim3(TPB), 0, stream>>>(feat, masks, out);
}